// Round 1
// baseline (491.555 us; speedup 1.0000x reference)
//
#include <hip/hip_runtime.h>
#include <cmath>

#define DEV __device__ __forceinline__

typedef __bf16 bf16x8 __attribute__((ext_vector_type(8)));
typedef float f32x4 __attribute__((ext_vector_type(4)));

DEV unsigned short f2bf(float f) {
  union { float f; unsigned int u; } v;
  v.f = f;
  unsigned int u = v.u;
  u += 0x7fffu + ((u >> 16) & 1u);   // RNE
  return (unsigned short)(u >> 16);
}

enum { ACT_ID = 0, ACT_ELU1 = 1, ACT_GELU = 2, ACT_ELU1S = 3 };

// Y[r,c] = act( sum_k X[r,k]*W[k,c] + bias[c] )
// X: [R,K] (fp32 or bf16 bits), W: [K,NC] fp32 row-major (in,out), Y: [R,NC]
// block = 256 threads = 4 waves, wave tile 64x64 (4x4 MFMA 16x16x32 tiles)
template <int BM, int BN, int K, int NC, int WR, int WC, int ACT, int ABF16, int OBF16>
__global__ __launch_bounds__(256)
void gemm_mfma(const void* __restrict__ Xv, const float* __restrict__ W,
               const float* __restrict__ bias, void* __restrict__ Yv, float scale)
{
  constexpr int BKP = 40;  // LDS k-stride (bf16 elems): 80B rows, 16B-aligned, conflict-light
  __shared__ __align__(16) unsigned short As[BM][BKP];
  __shared__ __align__(16) unsigned short Bs[BN][BKP];  // B stored transposed: Bs[col][k]
  constexpr int WMT = (BM / WR) / 16;
  constexpr int WNT = (BN / WC) / 16;
  static_assert(WMT == 4 && WNT == 4, "wave tile must be 64x64");
  static_assert((BM * 8) % 256 == 0, "A staging");

  const int tid = threadIdx.x;
  const int r0 = blockIdx.y * BM;
  const int c0 = blockIdx.x * BN;
  const int wv = tid >> 6, lane = tid & 63;
  const int wr = wv / WC, wc = wv % WC;
  const int lrow = lane & 15, lq = lane >> 4;
  const int kofs = lq * 8;
  const float* Xf = (const float*)Xv;
  const unsigned short* Xh = (const unsigned short*)Xv;

  f32x4 acc[WMT][WNT] = {};

  for (int kt = 0; kt < K; kt += 32) {
    // ---- stage A tile [BM x 32], row-major, fp32->bf16 in regs ----
#pragma unroll
    for (int it = 0; it < BM / 32; ++it) {
      int s = tid + 256 * it;
      int row = s >> 3;
      int kg = (s & 7) * 4;
      long gi = (long)(r0 + row) * K + kt + kg;
      ushort4 w;
      if (ABF16) {
        w = *(const ushort4*)(Xh + gi);
      } else {
        float4 d = *(const float4*)(Xf + gi);
        w.x = f2bf(d.x); w.y = f2bf(d.y); w.z = f2bf(d.z); w.w = f2bf(d.w);
      }
      *(ushort4*)&As[row][kg] = w;
    }
    // ---- stage B tile [32 x BN] transposed into Bs[col][k] (4x4 reg transpose) ----
    for (int s = tid; s < 2 * BN; s += 256) {
      int kg4 = (s / (BN / 4)) * 4;
      int cg4 = (s % (BN / 4)) * 4;
      const float* wp = W + (long)(kt + kg4) * NC + c0 + cg4;
      float4 rr0 = *(const float4*)(wp);
      float4 rr1 = *(const float4*)(wp + NC);
      float4 rr2 = *(const float4*)(wp + 2 * NC);
      float4 rr3 = *(const float4*)(wp + 3 * NC);
      ushort4 w;
      w.x = f2bf(rr0.x); w.y = f2bf(rr1.x); w.z = f2bf(rr2.x); w.w = f2bf(rr3.x);
      *(ushort4*)&Bs[cg4 + 0][kg4] = w;
      w.x = f2bf(rr0.y); w.y = f2bf(rr1.y); w.z = f2bf(rr2.y); w.w = f2bf(rr3.y);
      *(ushort4*)&Bs[cg4 + 1][kg4] = w;
      w.x = f2bf(rr0.z); w.y = f2bf(rr1.z); w.z = f2bf(rr2.z); w.w = f2bf(rr3.z);
      *(ushort4*)&Bs[cg4 + 2][kg4] = w;
      w.x = f2bf(rr0.w); w.y = f2bf(rr1.w); w.z = f2bf(rr2.w); w.w = f2bf(rr3.w);
      *(ushort4*)&Bs[cg4 + 3][kg4] = w;
    }
    __syncthreads();
    // ---- fragments + MFMA ----
    // A frag: lane holds A[m = lane&15][k = (lane>>4)*8 + j]  (ds_read_b128)
    // B frag: lane holds B[k = (lane>>4)*8 + j][n = lane&15]  -> read Bs[col][k] contiguous
    bf16x8 af[WMT], bfr[WNT];
#pragma unroll
    for (int i = 0; i < WMT; ++i)
      af[i] = *(const bf16x8*)&As[wr * (BM / WR) + i * 16 + lrow][kofs];
#pragma unroll
    for (int j = 0; j < WNT; ++j)
      bfr[j] = *(const bf16x8*)&Bs[wc * (BN / WC) + j * 16 + lrow][kofs];
#pragma unroll
    for (int i = 0; i < WMT; ++i)
#pragma unroll
      for (int j = 0; j < WNT; ++j)
        acc[i][j] = __builtin_amdgcn_mfma_f32_16x16x32_bf16(af[i], bfr[j], acc[i][j], 0, 0, 0);
    __syncthreads();
  }
  // ---- epilogue: C/D layout col = lane&15, row = (lane>>4)*4 + reg ----
  float* Yf = (float*)Yv;
  unsigned short* Yh = (unsigned short*)Yv;
#pragma unroll
  for (int i = 0; i < WMT; ++i) {
#pragma unroll
    for (int j = 0; j < WNT; ++j) {
      int col = c0 + wc * (BN / WC) + j * 16 + lrow;
      float bv = bias[col];
#pragma unroll
      for (int p = 0; p < 4; ++p) {
        int row = r0 + wr * (BM / WR) + i * 16 + lq * 4 + p;
        float v = acc[i][j][p] + bv;
        if (ACT == ACT_ELU1) {
          v = (v > 0.f) ? (v + 1.f) : __expf(v);           // elu(x)+1
        } else if (ACT == ACT_GELU) {
          v = 0.5f * v * (1.f + erff(v * 0.7071067811865475f));  // exact gelu
        } else if (ACT == ACT_ELU1S) {
          v = (v > 0.f) ? (v + 1.f) : __expf(v);
          v *= scale;                                       // (elu+1)/M
        }
        long yi = (long)row * NC + col;
        if (OBF16) Yh[yi] = f2bf(v);
        else       Yf[yi] = v;
      }
    }
  }
}

// kv_context stage 1: per (b,h, m-split of 512): partial [64,64] = sum_m ka[m,d]*v[m,e]
// plus partial ksum[d]. fp32 outer-product with 16-m LDS tiles, 4x4 per thread.
__global__ __launch_bounds__(256)
void kv_stage1(const float* __restrict__ ka, const float* __restrict__ v,
               float* __restrict__ kvpart, float* __restrict__ kspart)
{
  const int bh = blockIdx.x;          // 0..31 = b*8+h
  const int sp = blockIdx.y;          // 0..7
  const int b = bh >> 3, h = bh & 7;
  const int m0 = sp * 512;
  __shared__ __align__(16) float kas[16][72];
  __shared__ __align__(16) float vs[16][72];
  const int t = threadIdx.x;
  const int tx = t & 15, ty = t >> 4;
  float acc[4][4] = {};
  float ks = 0.f;
  const long base = (long)b * 4096 * 512 + h * 64;
  const int lr = t >> 4, lc = (t & 15) * 4;
  for (int mt = 0; mt < 32; ++mt) {
    const long rowb = base + (long)(m0 + mt * 16 + lr) * 512 + lc;
    *(float4*)&kas[lr][lc] = *(const float4*)(ka + rowb);
    *(float4*)&vs[lr][lc]  = *(const float4*)(v + rowb);
    __syncthreads();
#pragma unroll
    for (int kk = 0; kk < 16; ++kk) {
      float4 a4 = *(const float4*)&kas[kk][ty * 4];
      float4 b4 = *(const float4*)&vs[kk][tx * 4];
      float a[4] = {a4.x, a4.y, a4.z, a4.w};
      float bb[4] = {b4.x, b4.y, b4.z, b4.w};
#pragma unroll
      for (int i = 0; i < 4; ++i)
#pragma unroll
        for (int j = 0; j < 4; ++j) acc[i][j] += a[i] * bb[j];
    }
    if (t < 64) {
#pragma unroll
      for (int kk = 0; kk < 16; ++kk) ks += kas[kk][t];
    }
    __syncthreads();
  }
  float* kvp = kvpart + ((long)sp * 32 + bh) * 4096;
#pragma unroll
  for (int i = 0; i < 4; ++i)
#pragma unroll
    for (int j = 0; j < 4; ++j) kvp[(ty * 4 + i) * 64 + tx * 4 + j] = acc[i][j];
  if (t < 64) kspart[(sp * 32 + bh) * 64 + t] = ks;
}

__global__ __launch_bounds__(256)
void kv_stage2(const float* __restrict__ kvpart, const float* __restrict__ kspart,
               float* __restrict__ kv, float* __restrict__ ksum)
{
  const int bh = blockIdx.x;
  const int t = threadIdx.x;
  for (int i = t; i < 4096; i += 256) {
    float s = 0.f;
#pragma unroll
    for (int sp = 0; sp < 8; ++sp) s += kvpart[((long)sp * 32 + bh) * 4096 + i];
    kv[(long)bh * 4096 + i] = s;
  }
  if (t < 64) {
    float s = 0.f;
#pragma unroll
    for (int sp = 0; sp < 8; ++sp) s += kspart[(sp * 32 + bh) * 64 + t];
    ksum[bh * 64 + t] = s;
  }
}

// out[b,n,h,e] = clamp( (sum_d q[b,n,h,d]*kv[b,h,d,e]) / max(denom,1e-6) )
// block: (n-chunk of 16) x (head pair) x b; kv pair + q half-rows in LDS.
__global__ __launch_bounds__(256)
void attn_out_kernel(const float* __restrict__ q, const float* __restrict__ kvc,
                     const float* __restrict__ ksum, float* __restrict__ attn)
{
  const int n0 = blockIdx.x * 16;
  const int h0 = blockIdx.y * 2;
  const int b = blockIdx.z;
  __shared__ __align__(16) float qs[16][132];
  __shared__ __align__(16) float kvs[8192];
  __shared__ float kss[128];
  __shared__ float dinv[16][2];
  const int t = threadIdx.x;
  for (int s = t; s < 512; s += 256) {
    int r = s >> 5, c4 = (s & 31) * 4;
    *(float4*)&qs[r][c4] =
        *(const float4*)(q + (long)(b * 4096 + n0 + r) * 512 + h0 * 64 + c4);
  }
  {
    const float4* kvg = (const float4*)(kvc + (long)(b * 8 + h0) * 4096);
    float4* kvsh = (float4*)kvs;
    for (int s = t; s < 2048; s += 256) kvsh[s] = kvg[s];
  }
  if (t < 128) kss[t] = ksum[(b * 8 + h0) * 64 + t];
  __syncthreads();
  if (t < 32) {
    int r = t >> 1, hl = t & 1;
    float s = 0.f;
#pragma unroll
    for (int d = 0; d < 64; ++d) s += qs[r][hl * 64 + d] * kss[hl * 64 + d];
    dinv[r][hl] = 1.f / fmaxf(s, 1e-6f);
  }
  __syncthreads();
  const int r = t >> 4;
  const int c = t & 15;
  const int hl = c >> 3;
  const int e0 = (c & 7) * 8;
  const float* kvh = kvs + hl * 4096 + e0;
  const float* qrow = &qs[r][hl * 64];
  float a0 = 0, a1 = 0, a2 = 0, a3 = 0, a4 = 0, a5 = 0, a6 = 0, a7 = 0;
#pragma unroll 8
  for (int d = 0; d < 64; ++d) {
    float qv = qrow[d];
    float4 k0 = *(const float4*)(kvh + d * 64);
    float4 k1 = *(const float4*)(kvh + d * 64 + 4);
    a0 += qv * k0.x; a1 += qv * k0.y; a2 += qv * k0.z; a3 += qv * k0.w;
    a4 += qv * k1.x; a5 += qv * k1.y; a6 += qv * k1.z; a7 += qv * k1.w;
  }
  const float di = dinv[r][hl];
  float o[8] = {a0 * di, a1 * di, a2 * di, a3 * di,
                a4 * di, a5 * di, a6 * di, a7 * di};
#pragma unroll
  for (int j = 0; j < 8; ++j) {
    float x = o[j];
    if (!(x == x)) x = 0.f;                       // nan_to_num
    o[j] = fminf(65000.f, fmaxf(-65000.f, x));    // clip
  }
  float* dst = attn + (long)(b * 4096 + n0 + r) * 512 + (h0 + hl) * 64 + e0;
  *(float4*)dst = make_float4(o[0], o[1], o[2], o[3]);
  *(float4*)(dst + 4) = make_float4(o[4], o[5], o[6], o[7]);
}

// ---- workspace layout (float offsets) ----
// buf0 q | buf1 k->kaug | buf2 v->attn | buf3 hidden(bf16) | kv partials etc.
static constexpr long OFF_Q   = 0;
static constexpr long OFF_K   = 8388608;
static constexpr long OFF_V   = 16777216;
static constexpr long OFF_H   = 25165824;  // 131072x128 bf16 = 8388608 floats worth
static constexpr long OFF_KVP = 33554432;  // 8*32*4096
static constexpr long OFF_KSP = 34603008;  // 8*32*64
static constexpr long OFF_KV  = 34619392;  // 32*4096
static constexpr long OFF_KS  = 34750464;  // 32*64

extern "C" void kernel_launch(void* const* d_in, const int* in_sizes, int n_in,
                              void* d_out, int out_size, void* d_ws, size_t ws_size,
                              hipStream_t stream)
{
  const float* query = (const float*)d_in[0];
  const float* key   = (const float*)d_in[1];
  const float* value = (const float*)d_in[2];
  const float* Wq = (const float*)d_in[3];
  const float* bq = (const float*)d_in[4];
  const float* Wk = (const float*)d_in[5];
  const float* bk = (const float*)d_in[6];
  const float* Wv = (const float*)d_in[7];
  const float* bv = (const float*)d_in[8];
  const float* W1 = (const float*)d_in[9];
  const float* b1 = (const float*)d_in[10];
  const float* W2 = (const float*)d_in[11];
  const float* b2 = (const float*)d_in[12];
  const float* Wo = (const float*)d_in[13];
  const float* bo = (const float*)d_in[14];

  float* ws = (float*)d_ws;
  float* qb   = ws + OFF_Q;
  float* kb   = ws + OFF_K;    // k, later overwritten by kaug_scaled
  float* vb   = ws + OFF_V;    // v, later overwritten by attn
  unsigned short* hid = (unsigned short*)(ws + OFF_H);
  float* kvp  = ws + OFF_KVP;
  float* ksp  = ws + OFF_KSP;
  float* kvc  = ws + OFF_KV;
  float* ksm  = ws + OFF_KS;

  dim3 blk(256);
  const float invM = 1.f / 4096.f;

  // q = elu(query@Wq+bq)+1 ; k = elu(key@Wk+bk)+1 ; v = value@Wv+bv
  gemm_mfma<128,128,512,512,2,2,ACT_ELU1,0,0><<<dim3(4,128), blk, 0, stream>>>(query, Wq, bq, qb, 1.f);
  gemm_mfma<128,128,512,512,2,2,ACT_ELU1,0,0><<<dim3(4,128), blk, 0, stream>>>(key,   Wk, bk, kb, 1.f);
  gemm_mfma<128,128,512,512,2,2,ACT_ID,  0,0><<<dim3(4,128), blk, 0, stream>>>(value, Wv, bv, vb, 1.f);
  // hidden = gelu(k@W1+b1) as bf16, rows = B*M*H = 131072, K=64 -> N=128
  gemm_mfma<128,128,64,128,2,2,ACT_GELU,0,1><<<dim3(1,1024), blk, 0, stream>>>(kb, W1, b1, hid, 1.f);
  // kaug_scaled = (elu(hidden@W2+b2)+1)/M  -> overwrites kb
  gemm_mfma<256,64,128,64,4,1,ACT_ELU1S,1,0><<<dim3(1,512), blk, 0, stream>>>(hid, W2, b2, kb, invM);
  // kv_context + k_sum (split-M partials then reduce)
  kv_stage1<<<dim3(32,8), blk, 0, stream>>>(kb, vb, kvp, ksp);
  kv_stage2<<<dim3(32),   blk, 0, stream>>>(kvp, ksp, kvc, ksm);
  // out/denom -> attn (overwrites vb)
  attn_out_kernel<<<dim3(256,4,4), blk, 0, stream>>>(qb, kvc, ksm, vb);
  // final projection -> d_out
  gemm_mfma<128,128,512,512,2,2,ACT_ID,0,0><<<dim3(4,128), blk, 0, stream>>>(vb, Wo, bo, (float*)d_out, 1.f);
}

// Round 2
// 338.204 us; speedup vs baseline: 1.4534x; 1.4534x over previous
//
#include <hip/hip_runtime.h>
#include <cmath>

#define DEV __device__ __forceinline__

typedef __bf16 bf16x8 __attribute__((ext_vector_type(8)));
typedef float f32x4 __attribute__((ext_vector_type(4)));
typedef unsigned int u32;
typedef unsigned short u16;

DEV u16 f2bf(float f) {
  union { float f; u32 u; } v;
  v.f = f;
  u32 u = v.u;
  u += 0x7fffu + ((u >> 16) & 1u);   // RNE
  return (u16)(u >> 16);
}
DEV float bf2f(u16 h) {
  union { u32 u; float f; } v;
  v.u = ((u32)h) << 16;
  return v.f;
}

// async global->LDS, 16B per lane; LDS dst is wave-uniform base + lane*16 (HW adds it)
DEV void async16(const u16* g, u16* l) {
  __builtin_amdgcn_global_load_lds((const __attribute__((address_space(1))) u32*)g,
                                   (__attribute__((address_space(3))) u32*)l, 16, 0, 0);
}

enum { ACT_ID = 0, ACT_ELU1 = 1, ACT_GELU = 2, ACT_ELU1S = 3 };

// ---------------------------------------------------------------------------
// m97-style bf16 GEMM: Y[r,c] = act( sum_k A[r,k]*W[k,c] + bias[c] )
// A: [R,K] bf16 row-major. Bt: [NC,K] bf16 row-major (= W^T). Y: [R,NC].
// 256 thr = 4 waves; wave tile 64x64 = 4x4 MFMA 16x16x32; BK=32, unpadded LDS
// (required: global_load_lds writes wave-uniform base + lane*16).
// ---------------------------------------------------------------------------
template <int BM, int BN, int K, int WR, int WC, int ACT, int OBF16>
__global__ __launch_bounds__(256)
void gemm_bf16(const u16* __restrict__ A, const u16* __restrict__ Bt,
               const float* __restrict__ bias, void* __restrict__ Yv,
               int NC, float scale)
{
  constexpr int AI = BM / 64;   // async insts per thread for A tile (BM*4 slots / 256)
  constexpr int BI = BN / 64;
  __shared__ u16 As[BM * 32];
  __shared__ u16 Bs[BN * 32];
  static_assert(WR * WC == 4, "4 waves");

  const int tid = threadIdx.x;
  const int wv = tid >> 6, lane = tid & 63;
  const int wr = wv / WC, wc = wv % WC;
  const int lrow = lane & 15, lq = lane >> 4;
  const long r0 = (long)blockIdx.y * BM;
  const int c0 = blockIdx.x * BN;

  f32x4 acc[4][4] = {};

  for (int kt = 0; kt < K; kt += 32) {
    // stage A [BM x 32] bf16: slot s covers bytes [s*16, s*16+16) = row s>>2, k-chunk s&3
#pragma unroll
    for (int i = 0; i < AI; ++i) {
      const int s = (wv * AI + i) * 64 + lane;
      async16(A + (r0 + (s >> 2)) * (long)K + kt + (s & 3) * 8,
              &As[(wv * AI + i) * 512]);
    }
    // stage B^T rows c0..c0+BN (k-contiguous)
#pragma unroll
    for (int i = 0; i < BI; ++i) {
      const int s = (wv * BI + i) * 64 + lane;
      async16(Bt + ((long)c0 + (s >> 2)) * K + kt + (s & 3) * 8,
              &Bs[(wv * BI + i) * 512]);
    }
    __syncthreads();
    // fragments: A[m=lane&15][k=lq*8+j], B[k=lq*8+j][n=lane&15] (from B^T rows)
    bf16x8 af[4], bfr[4];
#pragma unroll
    for (int i = 0; i < 4; ++i)
      af[i] = *(const bf16x8*)&As[(wr * 64 + i * 16 + lrow) * 32 + lq * 8];
#pragma unroll
    for (int j = 0; j < 4; ++j)
      bfr[j] = *(const bf16x8*)&Bs[(wc * 64 + j * 16 + lrow) * 32 + lq * 8];
#pragma unroll
    for (int i = 0; i < 4; ++i)
#pragma unroll
      for (int j = 0; j < 4; ++j)
        acc[i][j] = __builtin_amdgcn_mfma_f32_16x16x32_bf16(af[i], bfr[j], acc[i][j], 0, 0, 0);
    __syncthreads();
  }
  // epilogue: C/D layout col = lane&15, row = lq*4 + p
  float* Yf = (float*)Yv;
  u16* Yh = (u16*)Yv;
#pragma unroll
  for (int i = 0; i < 4; ++i) {
#pragma unroll
    for (int j = 0; j < 4; ++j) {
      const int col = c0 + wc * 64 + j * 16 + lrow;
      const float bv = bias[col];
#pragma unroll
      for (int p = 0; p < 4; ++p) {
        const long row = r0 + wr * 64 + i * 16 + lq * 4 + p;
        float v = acc[i][j][p] + bv;
        if (ACT == ACT_ELU1) {
          v = (v > 0.f) ? (v + 1.f) : __expf(v);                 // elu(x)+1
        } else if (ACT == ACT_GELU) {
          v = 0.5f * v * (1.f + erff(v * 0.7071067811865475f));  // exact gelu
        } else if (ACT == ACT_ELU1S) {
          v = (v > 0.f) ? (v + 1.f) : __expf(v);
          v *= scale;                                            // (elu+1)/M
        }
        const long yi = row * NC + col;
        if (OBF16) Yh[yi] = f2bf(v);
        else       Yf[yi] = v;
      }
    }
  }
}

// ---------------------------------------------------------------------------
// fp32 -> bf16 convert for query/key/value (blockIdx.y selects tensor)
// ---------------------------------------------------------------------------
__global__ __launch_bounds__(256)
void cvt_qkv(const float* __restrict__ s0, const float* __restrict__ s1,
             const float* __restrict__ s2, u16* __restrict__ d0,
             u16* __restrict__ d1, u16* __restrict__ d2)
{
  const float* s = blockIdx.y == 0 ? s0 : blockIdx.y == 1 ? s1 : s2;
  u16* d = blockIdx.y == 0 ? d0 : blockIdx.y == 1 ? d1 : d2;
  const long i = ((long)blockIdx.x * 256 + threadIdx.x) * 8;
  float4 a = *(const float4*)(s + i);
  float4 b = *(const float4*)(s + i + 4);
  ushort4 w0, w1;
  w0.x = f2bf(a.x); w0.y = f2bf(a.y); w0.z = f2bf(a.z); w0.w = f2bf(a.w);
  w1.x = f2bf(b.x); w1.y = f2bf(b.y); w1.z = f2bf(b.z); w1.w = f2bf(b.w);
  *(ushort4*)(d + i) = w0;
  *(ushort4*)(d + i + 4) = w1;
}

// ---------------------------------------------------------------------------
// weight transpose+convert: W [K,N] fp32 -> Wt [N,K] bf16, 64x64 LDS tiles
// ---------------------------------------------------------------------------
struct TArgs {
  const float* src[6];
  u16* dst[6];
  int K[6];
  int N[6];
};
__global__ __launch_bounds__(256)
void transpose_w(TArgs a)
{
  const int m = blockIdx.z;
  const int K = a.K[m], N = a.N[m];
  const int kt = blockIdx.y * 64, nt = blockIdx.x * 64;
  if (kt >= K || nt >= N) return;
  const float* src = a.src[m];
  u16* dst = a.dst[m];
  __shared__ u16 t[64][72];  // t[n_local][k_local], padded
  const int tx = threadIdx.x & 15, ty = threadIdx.x >> 4;
#pragma unroll
  for (int rr = 0; rr < 64; rr += 16) {
    const int k = kt + ty + rr;
    float4 v = *(const float4*)(src + (long)k * N + nt + tx * 4);
    t[tx * 4 + 0][ty + rr] = f2bf(v.x);
    t[tx * 4 + 1][ty + rr] = f2bf(v.y);
    t[tx * 4 + 2][ty + rr] = f2bf(v.z);
    t[tx * 4 + 3][ty + rr] = f2bf(v.w);
  }
  __syncthreads();
#pragma unroll
  for (int it = 0; it < 2; ++it) {
    const int s = threadIdx.x + it * 256;
    const int r = s >> 3, c = (s & 7) * 8;
    ushort4 u0 = *(ushort4*)&t[r][c];
    ushort4 u1 = *(ushort4*)&t[r][c + 4];
    *(ushort4*)(dst + (long)(nt + r) * K + kt + c) = u0;
    *(ushort4*)(dst + (long)(nt + r) * K + kt + c + 4) = u1;
  }
}

// ---------------------------------------------------------------------------
// kv_context stage 1 (bf16 in): per (b,h, m-split of 256):
// partial [64,64] = sum_m ka[m,d]*v[m,e]; partial ksum[d].
// ---------------------------------------------------------------------------
__global__ __launch_bounds__(256)
void kv_stage1(const u16* __restrict__ ka, const u16* __restrict__ v,
               float* __restrict__ kvpart, float* __restrict__ kspart)
{
  const int bh = blockIdx.x;          // 0..31
  const int sp = blockIdx.y;          // 0..15
  const int b = bh >> 3, h = bh & 7;
  const int m0 = sp * 256;
  __shared__ __align__(16) float kas[16][68];
  __shared__ __align__(16) float vs[16][68];
  const int t = threadIdx.x;
  const int tx = t & 15, ty = t >> 4;
  float acc[4][4] = {};
  float ks = 0.f;
  const long base = (long)b * 4096 * 512 + h * 64;
  for (int mt = 0; mt < 16; ++mt) {
    const long rowb = base + (long)(m0 + mt * 16 + ty) * 512 + tx * 4;
    ushort4 ua = *(const ushort4*)(ka + rowb);
    ushort4 uv = *(const ushort4*)(v + rowb);
    kas[ty][tx * 4 + 0] = bf2f(ua.x); kas[ty][tx * 4 + 1] = bf2f(ua.y);
    kas[ty][tx * 4 + 2] = bf2f(ua.z); kas[ty][tx * 4 + 3] = bf2f(ua.w);
    vs[ty][tx * 4 + 0] = bf2f(uv.x); vs[ty][tx * 4 + 1] = bf2f(uv.y);
    vs[ty][tx * 4 + 2] = bf2f(uv.z); vs[ty][tx * 4 + 3] = bf2f(uv.w);
    __syncthreads();
#pragma unroll
    for (int kk = 0; kk < 16; ++kk) {
      float4 a4 = *(const float4*)&kas[kk][ty * 4];
      float4 b4 = *(const float4*)&vs[kk][tx * 4];
      float aa[4] = {a4.x, a4.y, a4.z, a4.w};
      float bb[4] = {b4.x, b4.y, b4.z, b4.w};
#pragma unroll
      for (int i = 0; i < 4; ++i)
#pragma unroll
        for (int j = 0; j < 4; ++j) acc[i][j] += aa[i] * bb[j];
    }
    if (t < 64) {
#pragma unroll
      for (int kk = 0; kk < 16; ++kk) ks += kas[kk][t];
    }
    __syncthreads();
  }
  float* kvp = kvpart + ((long)sp * 32 + bh) * 4096;
#pragma unroll
  for (int i = 0; i < 4; ++i)
#pragma unroll
    for (int j = 0; j < 4; ++j) kvp[(ty * 4 + i) * 64 + tx * 4 + j] = acc[i][j];
  if (t < 64) kspart[(sp * 32 + bh) * 64 + t] = ks;
}

__global__ __launch_bounds__(256)
void kv_stage2(const float* __restrict__ kvpart, const float* __restrict__ kspart,
               float* __restrict__ kv, float* __restrict__ ksum)
{
  const int bh = blockIdx.x;
  const int t = threadIdx.x;
  for (int i = t; i < 4096; i += 256) {
    float s = 0.f;
#pragma unroll
    for (int sp = 0; sp < 16; ++sp) s += kvpart[((long)sp * 32 + bh) * 4096 + i];
    kv[(long)bh * 4096 + i] = s;
  }
  if (t < 64) {
    float s = 0.f;
#pragma unroll
    for (int sp = 0; sp < 16; ++sp) s += kspart[(sp * 32 + bh) * 64 + t];
    ksum[bh * 64 + t] = s;
  }
}

// ---------------------------------------------------------------------------
// attn out (bf16 q in, bf16 out): out = clamp((q@kv) / max(q@ksum,1e-6))
// ---------------------------------------------------------------------------
__global__ __launch_bounds__(256)
void attn_out_kernel(const u16* __restrict__ q, const float* __restrict__ kvc,
                     const float* __restrict__ ksum, u16* __restrict__ attn)
{
  const int n0 = blockIdx.x * 16;
  const int h0 = blockIdx.y * 2;
  const int b = blockIdx.z;
  __shared__ __align__(16) float qs[16][132];
  __shared__ __align__(16) float kvs[8192];
  __shared__ float kss[128];
  __shared__ float dinv[16][2];
  const int t = threadIdx.x;
  for (int s = t; s < 512; s += 256) {
    const int r = s >> 5, c4 = (s & 31) * 4;
    ushort4 uq = *(const ushort4*)(q + (long)(b * 4096 + n0 + r) * 512 + h0 * 64 + c4);
    qs[r][c4 + 0] = bf2f(uq.x); qs[r][c4 + 1] = bf2f(uq.y);
    qs[r][c4 + 2] = bf2f(uq.z); qs[r][c4 + 3] = bf2f(uq.w);
  }
  {
    const float4* kvg = (const float4*)(kvc + (long)(b * 8 + h0) * 4096);
    float4* kvsh = (float4*)kvs;
    for (int s = t; s < 2048; s += 256) kvsh[s] = kvg[s];
  }
  if (t < 128) kss[t] = ksum[(b * 8 + h0) * 64 + t];
  __syncthreads();
  if (t < 32) {
    const int r = t >> 1, hl = t & 1;
    float s = 0.f;
#pragma unroll
    for (int d = 0; d < 64; ++d) s += qs[r][hl * 64 + d] * kss[hl * 64 + d];
    dinv[r][hl] = 1.f / fmaxf(s, 1e-6f);
  }
  __syncthreads();
  const int r = t >> 4;
  const int c = t & 15;
  const int hl = c >> 3;
  const int e0 = (c & 7) * 8;
  const float* kvh = kvs + hl * 4096 + e0;
  const float* qrow = &qs[r][hl * 64];
  float a0 = 0, a1 = 0, a2 = 0, a3 = 0, a4 = 0, a5 = 0, a6 = 0, a7 = 0;
#pragma unroll 8
  for (int d = 0; d < 64; ++d) {
    const float qv = qrow[d];
    float4 k0 = *(const float4*)(kvh + d * 64);
    float4 k1 = *(const float4*)(kvh + d * 64 + 4);
    a0 += qv * k0.x; a1 += qv * k0.y; a2 += qv * k0.z; a3 += qv * k0.w;
    a4 += qv * k1.x; a5 += qv * k1.y; a6 += qv * k1.z; a7 += qv * k1.w;
  }
  const float di = dinv[r][hl];
  float o[8] = {a0 * di, a1 * di, a2 * di, a3 * di,
                a4 * di, a5 * di, a6 * di, a7 * di};
  ushort4 w0, w1;
#pragma unroll
  for (int j = 0; j < 8; ++j) {
    float x = o[j];
    if (!(x == x)) x = 0.f;
    o[j] = fminf(65000.f, fmaxf(-65000.f, x));
  }
  w0.x = f2bf(o[0]); w0.y = f2bf(o[1]); w0.z = f2bf(o[2]); w0.w = f2bf(o[3]);
  w1.x = f2bf(o[4]); w1.y = f2bf(o[5]); w1.z = f2bf(o[6]); w1.w = f2bf(o[7]);
  u16* dst = attn + (long)(b * 4096 + n0 + r) * 512 + (h0 + hl) * 64 + e0;
  *(ushort4*)dst = w0;
  *(ushort4*)(dst + 4) = w1;
}

// ---------------------------------------------------------------------------
// workspace layout (U = 8388608 bf16 elems = one [4,4096,512] tensor)
// R1..R6 bf16 regions; fp32 region after; weight bf16 region last.  ~112 MB.
// ---------------------------------------------------------------------------
static constexpr long U = 8388608;

extern "C" void kernel_launch(void* const* d_in, const int* in_sizes, int n_in,
                              void* d_out, int out_size, void* d_ws, size_t ws_size,
                              hipStream_t stream)
{
  const float* query = (const float*)d_in[0];
  const float* key   = (const float*)d_in[1];
  const float* value = (const float*)d_in[2];
  const float* Wq = (const float*)d_in[3];
  const float* bq = (const float*)d_in[4];
  const float* Wk = (const float*)d_in[5];
  const float* bk = (const float*)d_in[6];
  const float* Wv = (const float*)d_in[7];
  const float* bv = (const float*)d_in[8];
  const float* W1 = (const float*)d_in[9];
  const float* b1 = (const float*)d_in[10];
  const float* W2 = (const float*)d_in[11];
  const float* b2 = (const float*)d_in[12];
  const float* Wo = (const float*)d_in[13];
  const float* bo = (const float*)d_in[14];

  u16* wsh = (u16*)d_ws;
  u16* qbf  = wsh;           // R1: cvt(query); later hid lower half
  u16* kbf  = wsh + U;       // R2: cvt(key);   later hid upper half
  u16* vbf  = wsh + 2 * U;   // R3: cvt(value); later kscaled
  u16* qact = wsh + 3 * U;   // R4
  u16* kact = wsh + 4 * U;   // R5: later attn
  u16* vact = wsh + 5 * U;   // R6
  u16* hid     = qbf;        // [131072,128] bf16 = 2U, overlays R1+R2
  u16* kscaled = vbf;        // overlays R3
  u16* attn    = kact;       // overlays R5

  float* fp   = (float*)(wsh + 6 * U);
  float* kvp  = fp;                    // 16*32*4096
  float* ksp  = fp + 2097152;          // 16*32*64
  float* kvc  = fp + 2129920;          // 32*4096
  float* ksm  = fp + 2260992;          // 32*64
  u16* wtb  = (u16*)(fp + 2263040);
  u16* WqT = wtb;                      // [512,512]
  u16* WkT = wtb + 262144;
  u16* WvT = wtb + 524288;
  u16* WoT = wtb + 786432;
  u16* W1T = wtb + 1048576;            // [128,64]
  u16* W2T = wtb + 1056768;            // [64,128]

  dim3 blk(256);
  const float invM = 1.f / 4096.f;

  // weight transpose+convert (6 matrices)
  TArgs ta;
  ta.src[0] = Wq; ta.dst[0] = WqT; ta.K[0] = 512; ta.N[0] = 512;
  ta.src[1] = Wk; ta.dst[1] = WkT; ta.K[1] = 512; ta.N[1] = 512;
  ta.src[2] = Wv; ta.dst[2] = WvT; ta.K[2] = 512; ta.N[2] = 512;
  ta.src[3] = Wo; ta.dst[3] = WoT; ta.K[3] = 512; ta.N[3] = 512;
  ta.src[4] = W1; ta.dst[4] = W1T; ta.K[4] = 64;  ta.N[4] = 128;
  ta.src[5] = W2; ta.dst[5] = W2T; ta.K[5] = 128; ta.N[5] = 64;
  transpose_w<<<dim3(8, 8, 6), blk, 0, stream>>>(ta);

  // activations -> bf16
  cvt_qkv<<<dim3(4096, 3), blk, 0, stream>>>(query, key, value, qbf, kbf, vbf);

  // projections (A bf16, W^T bf16): q/k get elu+1, v identity
  gemm_bf16<128,128,512,2,2,ACT_ELU1,1><<<dim3(4,128), blk, 0, stream>>>(qbf, WqT, bq, qact, 512, 1.f);
  gemm_bf16<128,128,512,2,2,ACT_ELU1,1><<<dim3(4,128), blk, 0, stream>>>(kbf, WkT, bk, kact, 512, 1.f);
  gemm_bf16<128,128,512,2,2,ACT_ID,  1><<<dim3(4,128), blk, 0, stream>>>(vbf, WvT, bv, vact, 512, 1.f);
  // hidden = gelu(k@W1+b1): rows=B*M*H=131072, K=64, N=128  (R5 -> R1R2)
  gemm_bf16<128,128,64,2,2,ACT_GELU,1><<<dim3(1,1024), blk, 0, stream>>>(kact, W1T, b1, hid, 128, 1.f);
  // kscaled = (elu(hid@W2+b2)+1)/M: K=128, N=64  (R1R2 -> R3)
  gemm_bf16<256,64,128,4,1,ACT_ELU1S,1><<<dim3(1,512), blk, 0, stream>>>(hid, W2T, b2, kscaled, 64, invM);
  // kv_context + k_sum
  kv_stage1<<<dim3(32,16), blk, 0, stream>>>(kscaled, vact, kvp, ksp);
  kv_stage2<<<dim3(32),    blk, 0, stream>>>(kvp, ksp, kvc, ksm);
  // attention output (R4 -> R5)
  attn_out_kernel<<<dim3(256,4,4), blk, 0, stream>>>(qact, kvc, ksm, attn);
  // final projection -> d_out (fp32)
  gemm_bf16<128,128,512,2,2,ACT_ID,0><<<dim3(4,128), blk, 0, stream>>>(attn, WoT, bo, (float*)d_out, 512, 1.f);
}

// Round 3
// 296.572 us; speedup vs baseline: 1.6575x; 1.1404x over previous
//
#include <hip/hip_runtime.h>
#include <cmath>

#define DEV __device__ __forceinline__

typedef __bf16 bf16x8 __attribute__((ext_vector_type(8)));
typedef float f32x4 __attribute__((ext_vector_type(4)));
typedef unsigned int u32;
typedef unsigned short u16;

DEV u16 f2bf(float f) {
  union { float f; u32 u; } v;
  v.f = f;
  u32 u = v.u;
  u += 0x7fffu + ((u >> 16) & 1u);   // RNE
  return (u16)(u >> 16);
}
DEV float bf2f(u16 h) {
  union { u32 u; float f; } v;
  v.u = ((u32)h) << 16;
  return v.f;
}

// async global->LDS, 16B per lane; LDS dst is wave-uniform base + lane*16
DEV void async16(const u16* g, u16* l) {
  __builtin_amdgcn_global_load_lds((const __attribute__((address_space(1))) u32*)g,
                                   (__attribute__((address_space(3))) u32*)l, 16, 0, 0);
}

enum { ACT_ID = 0, ACT_ELU1 = 1, ACT_GELU = 2, ACT_ELU1S = 3 };
enum { AM_ROW = 0, AM_BH = 1 };     // A row addressing: plain rows | per-(b,h) m-rows of hid
enum { OM_ROW = 0, OM_VT = 1, OM_KAT = 2 };  // output: row-major | vT[b][h][e][m] | kaT[bh][d][m]

DEV float apply_act(int ACT, float v, float scale) {
  if (ACT == ACT_ELU1)  return (v > 0.f) ? (v + 1.f) : __expf(v);
  if (ACT == ACT_GELU)  return 0.5f * v * (1.f + erff(v * 0.7071067811865475f));
  if (ACT == ACT_ELU1S) return ((v > 0.f) ? (v + 1.f) : __expf(v)) * scale;
  return v;
}

// ---------------------------------------------------------------------------
// m97-style bf16 GEMM. A: bf16 (addressing per AMODE). Bt: [NC,K] bf16 (=W^T).
// 256 thr = 4 waves; wave tile 64x64 = 4x4 MFMA 16x16x32; BK=32 unpadded LDS.
// ---------------------------------------------------------------------------
template <int BM, int BN, int K, int WR, int WC, int ACT, int OBF16, int AMODE, int OMODE>
__global__ __launch_bounds__(256)
void gemm_bf16(const u16* __restrict__ A, const u16* __restrict__ Bt,
               const float* __restrict__ bias, void* __restrict__ Yv,
               int NC, float scale)
{
  constexpr int AI = BM / 64;
  constexpr int BI = BN / 64;
  __shared__ u16 As[BM * 32];
  __shared__ u16 Bs[BN * 32];
  static_assert(WR * WC == 4, "4 waves");

  const int tid = threadIdx.x;
  const int wv = tid >> 6, lane = tid & 63;
  const int wr = wv / WC, wc = wv % WC;
  const int lrow = lane & 15, lq = lane >> 4;
  const int c0 = blockIdx.x * BN;

  long arow_base;
  int arstride;
  long r0 = 0;
  int bh = 0, m0 = 0;
  if (AMODE == AM_ROW) {
    r0 = (long)blockIdx.y * BM;
    arow_base = r0 * K;
    arstride = K;
  } else {
    bh = blockIdx.y >> 4;               // 0..31
    m0 = (blockIdx.y & 15) * BM;        // m tile within (b,h)
    const int b = bh >> 3, h = bh & 7;
    arow_base = (long)b * 4194304 + (long)h * 128 + (long)m0 * 1024;  // hid[(b,m,h)][128]
    arstride = 1024;
  }

  f32x4 acc[4][4] = {};

  for (int kt = 0; kt < K; kt += 32) {
#pragma unroll
    for (int i = 0; i < AI; ++i) {
      const int s = (wv * AI + i) * 64 + lane;
      async16(A + arow_base + (long)(s >> 2) * arstride + kt + (s & 3) * 8,
              &As[(wv * AI + i) * 512]);
    }
#pragma unroll
    for (int i = 0; i < BI; ++i) {
      const int s = (wv * BI + i) * 64 + lane;
      async16(Bt + ((long)c0 + (s >> 2)) * K + kt + (s & 3) * 8,
              &Bs[(wv * BI + i) * 512]);
    }
    __syncthreads();
    bf16x8 af[4], bfr[4];
#pragma unroll
    for (int i = 0; i < 4; ++i)
      af[i] = *(const bf16x8*)&As[(wr * 64 + i * 16 + lrow) * 32 + lq * 8];
#pragma unroll
    for (int j = 0; j < 4; ++j)
      bfr[j] = *(const bf16x8*)&Bs[(wc * 64 + j * 16 + lrow) * 32 + lq * 8];
#pragma unroll
    for (int i = 0; i < 4; ++i)
#pragma unroll
      for (int j = 0; j < 4; ++j)
        acc[i][j] = __builtin_amdgcn_mfma_f32_16x16x32_bf16(af[i], bfr[j], acc[i][j], 0, 0, 0);
    __syncthreads();
  }

  float* Yf = (float*)Yv;
  u16* Yh = (u16*)Yv;
#pragma unroll
  for (int i = 0; i < 4; ++i) {
#pragma unroll
    for (int j = 0; j < 4; ++j) {
      const int col = c0 + wc * 64 + j * 16 + lrow;
      const float bv = bias[col];
      float o[4];
#pragma unroll
      for (int p = 0; p < 4; ++p) o[p] = apply_act(ACT, acc[i][j][p] + bv, scale);

      if (OMODE == OM_ROW) {
#pragma unroll
        for (int p = 0; p < 4; ++p) {
          const long row = r0 + wr * 64 + i * 16 + lq * 4 + p;
          const long yi = row * NC + col;
          if (OBF16) Yh[yi] = f2bf(o[p]);
          else       Yf[yi] = o[p];
        }
      } else if (OMODE == OM_VT) {
        // vT[b][h][e][m]: lane's 4 values are consecutive m
        const int b = (int)(r0 >> 12);
        const int m = (int)(r0 & 4095) + wr * 64 + i * 16 + lq * 4;
        const int h = col >> 6, e = col & 63;
        ushort4 w;
        w.x = f2bf(o[0]); w.y = f2bf(o[1]); w.z = f2bf(o[2]); w.w = f2bf(o[3]);
        *(ushort4*)(Yh + (((long)b * 8 + h) * 64 + e) * 4096 + m) = w;
      } else {  // OM_KAT: kaT[bh][d][m]
        const int m = m0 + wr * 64 + i * 16 + lq * 4;
        ushort4 w;
        w.x = f2bf(o[0]); w.y = f2bf(o[1]); w.z = f2bf(o[2]); w.w = f2bf(o[3]);
        *(ushort4*)(Yh + ((long)bh * 64 + col) * 4096 + m) = w;
      }
    }
  }
}

// ---------------------------------------------------------------------------
// fp32 -> bf16 convert for query/key/value
// ---------------------------------------------------------------------------
__global__ __launch_bounds__(256)
void cvt_qkv(const float* __restrict__ s0, const float* __restrict__ s1,
             const float* __restrict__ s2, u16* __restrict__ d0,
             u16* __restrict__ d1, u16* __restrict__ d2)
{
  const float* s = blockIdx.y == 0 ? s0 : blockIdx.y == 1 ? s1 : s2;
  u16* d = blockIdx.y == 0 ? d0 : blockIdx.y == 1 ? d1 : d2;
  const long i = ((long)blockIdx.x * 256 + threadIdx.x) * 8;
  float4 a = *(const float4*)(s + i);
  float4 b = *(const float4*)(s + i + 4);
  ushort4 w0, w1;
  w0.x = f2bf(a.x); w0.y = f2bf(a.y); w0.z = f2bf(a.z); w0.w = f2bf(a.w);
  w1.x = f2bf(b.x); w1.y = f2bf(b.y); w1.z = f2bf(b.z); w1.w = f2bf(b.w);
  *(ushort4*)(d + i) = w0;
  *(ushort4*)(d + i + 4) = w1;
}

// ---------------------------------------------------------------------------
// weight transpose+convert: W [K,N] fp32 -> Wt [N,K] bf16
// ---------------------------------------------------------------------------
struct TArgs {
  const float* src[6];
  u16* dst[6];
  int K[6];
  int N[6];
};
__global__ __launch_bounds__(256)
void transpose_w(TArgs a)
{
  const int m = blockIdx.z;
  const int K = a.K[m], N = a.N[m];
  const int kt = blockIdx.y * 64, nt = blockIdx.x * 64;
  if (kt >= K || nt >= N) return;
  const float* src = a.src[m];
  u16* dst = a.dst[m];
  __shared__ u16 t[64][72];
  const int tx = threadIdx.x & 15, ty = threadIdx.x >> 4;
#pragma unroll
  for (int rr = 0; rr < 64; rr += 16) {
    const int k = kt + ty + rr;
    float4 v = *(const float4*)(src + (long)k * N + nt + tx * 4);
    t[tx * 4 + 0][ty + rr] = f2bf(v.x);
    t[tx * 4 + 1][ty + rr] = f2bf(v.y);
    t[tx * 4 + 2][ty + rr] = f2bf(v.z);
    t[tx * 4 + 3][ty + rr] = f2bf(v.w);
  }
  __syncthreads();
#pragma unroll
  for (int it = 0; it < 2; ++it) {
    const int s = threadIdx.x + it * 256;
    const int r = s >> 3, c = (s & 7) * 8;
    ushort4 u0 = *(ushort4*)&t[r][c];
    ushort4 u1 = *(ushort4*)&t[r][c + 4];
    *(ushort4*)(dst + (long)(nt + r) * K + kt + c) = u0;
    *(ushort4*)(dst + (long)(nt + r) * K + kt + c + 4) = u1;
  }
}

// ---------------------------------------------------------------------------
// kv GEMM: D[d][e] = sum_m kaT[bh][d][m] * vT-as-B  (K = m, split 8 ways)
// Also ksum[d] via all-ones B fragment. Partials in fp32.
// grid (8 ksplit, 32 bh), 256 thr = 4 waves, each wave owns one 32-m chunk/phase.
// ---------------------------------------------------------------------------
__global__ __launch_bounds__(256)
void kv_gemm(const u16* __restrict__ kaT, const u16* __restrict__ vT,
             float* __restrict__ kvp, float* __restrict__ ksp)
{
  const int sp = blockIdx.x;   // 0..7
  const int bh = blockIdx.y;   // 0..31
  __shared__ u16 SB[16384];    // As[4][64][32] | Bs[4][64][32]; fp32 red overlays
  u16* As = SB;
  u16* Bs = SB + 8192;
  const int tid = threadIdx.x, wv = tid >> 6, lane = tid & 63;
  const int lrow = lane & 15, lq = lane >> 4;
  f32x4 acc[4][4] = {};
  f32x4 accs[4] = {};
  bf16x8 ones;
#pragma unroll
  for (int z = 0; z < 8; ++z) ones[z] = (__bf16)1.0f;
  const long base = (long)bh * 64 * 4096;

  for (int ph = 0; ph < 4; ++ph) {
    const int m0 = sp * 512 + ph * 128;
#pragma unroll
    for (int i = 0; i < 4; ++i) {
      const int s = (wv * 4 + i) * 64 + lane;
      const int chunk = s >> 8, row = (s >> 2) & 63, part = s & 3;
      const long g = base + (long)row * 4096 + m0 + chunk * 32 + part * 8;
      async16(kaT + g, &As[(wv * 4 + i) * 512]);
      async16(vT + g, &Bs[(wv * 4 + i) * 512]);
    }
    __syncthreads();
    bf16x8 af[4], bfr[4];
#pragma unroll
    for (int i = 0; i < 4; ++i)
      af[i] = *(const bf16x8*)&As[wv * 2048 + (i * 16 + lrow) * 32 + lq * 8];
#pragma unroll
    for (int j = 0; j < 4; ++j)
      bfr[j] = *(const bf16x8*)&Bs[wv * 2048 + (j * 16 + lrow) * 32 + lq * 8];
#pragma unroll
    for (int i = 0; i < 4; ++i) {
#pragma unroll
      for (int j = 0; j < 4; ++j)
        acc[i][j] = __builtin_amdgcn_mfma_f32_16x16x32_bf16(af[i], bfr[j], acc[i][j], 0, 0, 0);
      accs[i] = __builtin_amdgcn_mfma_f32_16x16x32_bf16(af[i], ones, accs[i], 0, 0, 0);
    }
    __syncthreads();
  }

  // cross-wave reduce in LDS: red[e][68] fp32 (+ ksr[64]) overlaying SB
  float* red = (float*)SB;        // 64*68*4 = 17408 B
  float* ksr = red + 64 * 68;     // 64 floats
  for (int w = 0; w < 4; ++w) {
    __syncthreads();
    if (wv == w) {
#pragma unroll
      for (int i = 0; i < 4; ++i) {
#pragma unroll
        for (int j = 0; j < 4; ++j) {
          const int e = j * 16 + lrow, d0 = i * 16 + lq * 4;
          float* p = &red[e * 68 + d0];
          if (w == 0) { p[0] = acc[i][j][0]; p[1] = acc[i][j][1]; p[2] = acc[i][j][2]; p[3] = acc[i][j][3]; }
          else        { p[0] += acc[i][j][0]; p[1] += acc[i][j][1]; p[2] += acc[i][j][2]; p[3] += acc[i][j][3]; }
        }
        if (lrow == 0) {
          const int d0 = i * 16 + lq * 4;
#pragma unroll
          for (int p2 = 0; p2 < 4; ++p2) {
            if (w == 0) ksr[d0 + p2] = accs[i][p2];
            else        ksr[d0 + p2] += accs[i][p2];
          }
        }
      }
    }
  }
  __syncthreads();
  float* kvo = kvp + ((long)sp * 32 + bh) * 4096;
  for (int s = tid; s < 4096; s += 256) kvo[s] = red[(s >> 6) * 68 + (s & 63)];
  if (tid < 64) ksp[(sp * 32 + bh) * 64 + tid] = ksr[tid];
}

__global__ __launch_bounds__(256)
void kv_reduce(const float* __restrict__ kvp, const float* __restrict__ ksp,
               u16* __restrict__ kvT, u16* __restrict__ ksumT)
{
  const int bh = blockIdx.x;
  const int t = threadIdx.x;
  for (int s = t; s < 4096; s += 256) {
    float v = 0.f;
#pragma unroll
    for (int sp = 0; sp < 8; ++sp) v += kvp[((long)sp * 32 + bh) * 4096 + s];
    kvT[(long)bh * 4096 + s] = f2bf(v);
  }
  if (t < 64) {
    float v = 0.f;
#pragma unroll
    for (int sp = 0; sp < 8; ++sp) v += ksp[(sp * 32 + bh) * 64 + t];
    ksumT[bh * 64 + t] = f2bf(v);
  }
}

// ---------------------------------------------------------------------------
// attn MFMA: per (bh, n-tile of 256): out[n][e] = (q@kv) / max(q@ksum,1e-6)
// q staged async16 as [2 khalf][256][32]; kvT[e][d]/ksum B-frags from global.
// LDS-bounce epilogue for coalesced row-major bf16 output.
// ---------------------------------------------------------------------------
__global__ __launch_bounds__(256)
void attn_mfma(const u16* __restrict__ q, const u16* __restrict__ kvT,
               const u16* __restrict__ ksumT, u16* __restrict__ attn)
{
  __shared__ u16 SB[17408];   // max(As 16384, bounce 4*64*68=17408)
  const int tid = threadIdx.x, wv = tid >> 6, lane = tid & 63;
  const int lrow = lane & 15, lq = lane >> 4;
  const int n0 = blockIdx.x * 256;
  const int bh = blockIdx.y, b = bh >> 3, h = bh & 7;
  u16* As = SB;

#pragma unroll
  for (int half = 0; half < 2; ++half)
#pragma unroll
    for (int i = 0; i < 4; ++i) {
      const int s = (wv * 4 + i) * 64 + lane;
      async16(q + ((long)(b * 4096 + n0 + (s >> 2))) * 512 + h * 64 + half * 32 + (s & 3) * 8,
              &As[half * 8192 + (wv * 4 + i) * 512]);
    }
  // B fragments from global (L2-hot: 8KB kvT per bh shared by 16 blocks)
  bf16x8 bfr[2][4], ks[2];
#pragma unroll
  for (int half = 0; half < 2; ++half) {
#pragma unroll
    for (int j = 0; j < 4; ++j)
      bfr[half][j] = *(const bf16x8*)(kvT + ((long)bh * 64 + j * 16 + lrow) * 64 + half * 32 + lq * 8);
    ks[half] = *(const bf16x8*)(ksumT + bh * 64 + half * 32 + lq * 8);
  }
  __syncthreads();

  f32x4 acc[4][4] = {};
  f32x4 accd[4] = {};
#pragma unroll
  for (int half = 0; half < 2; ++half) {
    bf16x8 af[4];
#pragma unroll
    for (int i = 0; i < 4; ++i)
      af[i] = *(const bf16x8*)&As[half * 8192 + (wv * 64 + i * 16 + lrow) * 32 + lq * 8];
#pragma unroll
    for (int i = 0; i < 4; ++i) {
#pragma unroll
      for (int j = 0; j < 4; ++j)
        acc[i][j] = __builtin_amdgcn_mfma_f32_16x16x32_bf16(af[i], bfr[half][j], acc[i][j], 0, 0, 0);
      accd[i] = __builtin_amdgcn_mfma_f32_16x16x32_bf16(af[i], ks[half], accd[i], 0, 0, 0);
    }
  }
  __syncthreads();   // done with As; reuse as bounce buffer

  // bounce: LT[wv][e=64][68 n-padded], transposed so lane writes ushort4 along n
  u16* LT = SB;
#pragma unroll
  for (int i = 0; i < 4; ++i) {
    float dinv[4];
#pragma unroll
    for (int p = 0; p < 4; ++p) dinv[p] = 1.f / fmaxf(accd[i][p], 1e-6f);
#pragma unroll
    for (int j = 0; j < 4; ++j) {
      const int e = j * 16 + lrow;
      const int nl0 = i * 16 + lq * 4;
      ushort4 w;
      float x0 = acc[i][j][0] * dinv[0], x1 = acc[i][j][1] * dinv[1];
      float x2 = acc[i][j][2] * dinv[2], x3 = acc[i][j][3] * dinv[3];
      if (!(x0 == x0)) x0 = 0.f;
      if (!(x1 == x1)) x1 = 0.f;
      if (!(x2 == x2)) x2 = 0.f;
      if (!(x3 == x3)) x3 = 0.f;
      w.x = f2bf(fminf(65000.f, fmaxf(-65000.f, x0)));
      w.y = f2bf(fminf(65000.f, fmaxf(-65000.f, x1)));
      w.z = f2bf(fminf(65000.f, fmaxf(-65000.f, x2)));
      w.w = f2bf(fminf(65000.f, fmaxf(-65000.f, x3)));
      *(ushort4*)&LT[wv * 4352 + e * 68 + nl0] = w;
    }
  }
  __syncthreads();
  // coalesced copy-out: 16B chunks of 8 e per (n)
#pragma unroll
  for (int it = 0; it < 8; ++it) {
    const int c = it * 256 + tid;           // 0..2047
    const int n = c & 255, ec = c >> 8;     // ec 0..7 -> e0 = ec*8
    const int wr2 = n >> 6, nl = n & 63;
    ushort4 w0, w1;
    w0.x = LT[wr2 * 4352 + (ec * 8 + 0) * 68 + nl];
    w0.y = LT[wr2 * 4352 + (ec * 8 + 1) * 68 + nl];
    w0.z = LT[wr2 * 4352 + (ec * 8 + 2) * 68 + nl];
    w0.w = LT[wr2 * 4352 + (ec * 8 + 3) * 68 + nl];
    w1.x = LT[wr2 * 4352 + (ec * 8 + 4) * 68 + nl];
    w1.y = LT[wr2 * 4352 + (ec * 8 + 5) * 68 + nl];
    w1.z = LT[wr2 * 4352 + (ec * 8 + 6) * 68 + nl];
    w1.w = LT[wr2 * 4352 + (ec * 8 + 7) * 68 + nl];
    u16* dst = attn + ((long)(b * 4096 + n0 + n)) * 512 + h * 64 + ec * 8;
    *(ushort4*)dst = w0;
    *(ushort4*)(dst + 4) = w1;
  }
}

// ---------------------------------------------------------------------------
static constexpr long U = 8388608;   // elems of one [4,4096,512] tensor

extern "C" void kernel_launch(void* const* d_in, const int* in_sizes, int n_in,
                              void* d_out, int out_size, void* d_ws, size_t ws_size,
                              hipStream_t stream)
{
  const float* query = (const float*)d_in[0];
  const float* key   = (const float*)d_in[1];
  const float* value = (const float*)d_in[2];
  const float* Wq = (const float*)d_in[3];
  const float* bq = (const float*)d_in[4];
  const float* Wk = (const float*)d_in[5];
  const float* bk = (const float*)d_in[6];
  const float* Wv = (const float*)d_in[7];
  const float* bv = (const float*)d_in[8];
  const float* W1 = (const float*)d_in[9];
  const float* b1 = (const float*)d_in[10];
  const float* W2 = (const float*)d_in[11];
  const float* b2 = (const float*)d_in[12];
  const float* Wo = (const float*)d_in[13];
  const float* bo = (const float*)d_in[14];

  u16* wsh = (u16*)d_ws;
  u16* qbf  = wsh;           // R1; later hid lower
  u16* kbf  = wsh + U;       // R2; later hid upper
  u16* vbf  = wsh + 2 * U;   // R3; later kaT
  u16* qact = wsh + 3 * U;   // R4
  u16* kact = wsh + 4 * U;   // R5; later attn
  u16* vT   = wsh + 5 * U;   // R6: vT[b][h][e][m]
  u16* hid  = qbf;           // [131072,128] bf16 = 2U
  u16* kaT  = vbf;           // [32][64][4096]
  u16* attn = kact;

  float* fp  = (float*)(wsh + 6 * U);
  float* kvp = fp;                     // 8*32*4096
  float* ksp = fp + 1048576;           // 8*32*64
  u16* kvTg   = (u16*)(fp + 1064960);  // 32*4096
  u16* ksumTg = kvTg + 131072;         // 32*64
  u16* wtb = ksumTg + 2048;
  u16* WqT = wtb;                      // [512,512]
  u16* WkT = wtb + 262144;
  u16* WvT = wtb + 524288;
  u16* WoT = wtb + 786432;
  u16* W1T = wtb + 1048576;            // [128,64]
  u16* W2T = wtb + 1056768;            // [64,128]

  dim3 blk(256);
  const float invM = 1.f / 4096.f;

  TArgs ta;
  ta.src[0] = Wq; ta.dst[0] = WqT; ta.K[0] = 512; ta.N[0] = 512;
  ta.src[1] = Wk; ta.dst[1] = WkT; ta.K[1] = 512; ta.N[1] = 512;
  ta.src[2] = Wv; ta.dst[2] = WvT; ta.K[2] = 512; ta.N[2] = 512;
  ta.src[3] = Wo; ta.dst[3] = WoT; ta.K[3] = 512; ta.N[3] = 512;
  ta.src[4] = W1; ta.dst[4] = W1T; ta.K[4] = 64;  ta.N[4] = 128;
  ta.src[5] = W2; ta.dst[5] = W2T; ta.K[5] = 128; ta.N[5] = 64;
  transpose_w<<<dim3(8, 8, 6), blk, 0, stream>>>(ta);

  cvt_qkv<<<dim3(4096, 3), blk, 0, stream>>>(query, key, value, qbf, kbf, vbf);

  // projections
  gemm_bf16<128,128,512,2,2,ACT_ELU1,1,AM_ROW,OM_ROW><<<dim3(4,128), blk, 0, stream>>>(qbf, WqT, bq, qact, 512, 1.f);
  gemm_bf16<128,128,512,2,2,ACT_ELU1,1,AM_ROW,OM_ROW><<<dim3(4,128), blk, 0, stream>>>(kbf, WkT, bk, kact, 512, 1.f);
  gemm_bf16<128,128,512,2,2,ACT_ID,  1,AM_ROW,OM_VT ><<<dim3(4,128), blk, 0, stream>>>(vbf, WvT, bv, vT,   512, 1.f);
  // MLP1: hid = gelu(kact @ W1 + b1), rows (b,m,h) = 131072, K=64, N=128
  gemm_bf16<128,128,64,2,2,ACT_GELU,1,AM_ROW,OM_ROW><<<dim3(1,1024), blk, 0, stream>>>(kact, W1T, b1, hid, 128, 1.f);
  // MLP2: kaT[bh][d][m] = (elu(hid@W2+b2)+1)/M, rows per (b,h)
  gemm_bf16<256,64,128,4,1,ACT_ELU1S,1,AM_BH,OM_KAT><<<dim3(1,512), blk, 0, stream>>>(hid, W2T, b2, kaT, 64, invM);
  // kv context + ksum (MFMA split-K) then reduce to bf16
  kv_gemm<<<dim3(8,32), blk, 0, stream>>>(kaT, vT, kvp, ksp);
  kv_reduce<<<dim3(32), blk, 0, stream>>>(kvp, ksp, kvTg, ksumTg);
  // attention output
  attn_mfma<<<dim3(16,32), blk, 0, stream>>>(qact, kvTg, ksumTg, attn);
  // final projection -> d_out fp32
  gemm_bf16<128,128,512,2,2,ACT_ID,0,AM_ROW,OM_ROW><<<dim3(4,128), blk, 0, stream>>>(attn, WoT, bo, (float*)d_out, 512, 1.f);
}

// Round 5
// 295.307 us; speedup vs baseline: 1.6646x; 1.0043x over previous
//
#include <hip/hip_runtime.h>
#include <cmath>

#define DEV __device__ __forceinline__

typedef __bf16 bf16x8 __attribute__((ext_vector_type(8)));
typedef float f32x4 __attribute__((ext_vector_type(4)));
typedef unsigned int u32;
typedef unsigned short u16;

DEV u16 f2bf(float f) {
  union { float f; u32 u; } v;
  v.f = f;
  u32 u = v.u;
  u += 0x7fffu + ((u >> 16) & 1u);   // RNE
  return (u16)(u >> 16);
}
DEV __bf16 bfbits(u16 b) {
  union { u16 u; __bf16 h; } v;
  v.u = b;
  return v.h;
}

// async global->LDS, 16B per lane; LDS dst is wave-uniform base + lane*16
DEV void async16(const void* g, void* l) {
  __builtin_amdgcn_global_load_lds((const __attribute__((address_space(1))) u32*)g,
                                   (__attribute__((address_space(3))) u32*)l, 16, 0, 0);
}

enum { ACT_ID = 0, ACT_ELU1 = 1, ACT_GELU = 2, ACT_ELU1S = 3 };
enum { OM_ROW = 0, OM_VT = 1 };   // row-major | vT[b][h][e][m]

DEV float apply_act(int ACT, float v, float scale) {
  if (ACT == ACT_ELU1)  return (v > 0.f) ? (v + 1.f) : __expf(v);
  if (ACT == ACT_GELU)  return 0.5f * v * (1.f + erff(v * 0.7071067811865475f));
  if (ACT == ACT_ELU1S) return ((v > 0.f) ? (v + 1.f) : __expf(v)) * scale;
  return v;
}

// ---------------------------------------------------------------------------
// m97-style GEMM. A: [R,K] fp32 (AFP32=1, staged raw + in-reg RNE cvt) or bf16.
// Bt: [NC,K] bf16 (= W^T). 256 thr = 4 waves; wave tile 64x64; BK=32.
// fp32 A uses XOR part-swizzle so b128 LDS reads stay bank-balanced.
// ---------------------------------------------------------------------------
template <int BM, int BN, int K, int WR, int WC, int ACT, int OBF16, int OMODE, int AFP32>
__global__ __launch_bounds__(256)
void gemm_bf16(const void* __restrict__ Av, const u16* __restrict__ Bt,
               const float* __restrict__ bias, void* __restrict__ Yv,
               int NC, float scale)
{
  constexpr int AI = AFP32 ? BM / 32 : BM / 64;   // async insts/thread for A tile
  constexpr int BI = BN / 64;
  constexpr int ABYTES = AFP32 ? BM * 128 : BM * 64;
  __shared__ __align__(16) char AsRaw[ABYTES];
  __shared__ u16 Bs[BN * 32];
  static_assert(WR * WC == 4, "4 waves");

  const int tid = threadIdx.x;
  const int wv = tid >> 6, lane = tid & 63;
  const int wr = wv / WC, wc = wv % WC;
  const int lrow = lane & 15, lq = lane >> 4;
  const int c0 = blockIdx.x * BN;
  const long r0 = (long)blockIdx.y * BM;
  const float* Af = (const float*)Av;
  const u16* Ah = (const u16*)Av;

  f32x4 acc[4][4] = {};

  for (int kt = 0; kt < K; kt += 32) {
    if (AFP32) {
#pragma unroll
      for (int i = 0; i < AI; ++i) {
        const int s = (wv * AI + i) * 64 + lane;
        const int row = s >> 3, p = s & 7;
        const int gp = p ^ (row & 7);          // XOR swizzle
        async16(Af + (r0 + row) * K + kt + gp * 4, AsRaw + (wv * AI + i) * 1024);
      }
    } else {
#pragma unroll
      for (int i = 0; i < AI; ++i) {
        const int s = (wv * AI + i) * 64 + lane;
        async16(Ah + (r0 + (s >> 2)) * (long)K + kt + (s & 3) * 8,
                AsRaw + (wv * AI + i) * 1024);
      }
    }
#pragma unroll
    for (int i = 0; i < BI; ++i) {
      const int s = (wv * BI + i) * 64 + lane;
      async16(Bt + ((long)c0 + (s >> 2)) * K + kt + (s & 3) * 8,
              (char*)Bs + (wv * BI + i) * 1024);
    }
    __syncthreads();
    bf16x8 af[4], bfr[4];
#pragma unroll
    for (int i = 0; i < 4; ++i) {
      const int r = wr * 64 + i * 16 + lrow;
      if (AFP32) {
        const float* Asf = (const float*)AsRaw;
        const int r7 = r & 7, P0 = lq * 2;
        float4 lo = *(const float4*)&Asf[r * 32 + (P0 ^ r7) * 4];
        float4 hi = *(const float4*)&Asf[r * 32 + ((P0 + 1) ^ r7) * 4];
        af[i][0] = bfbits(f2bf(lo.x)); af[i][1] = bfbits(f2bf(lo.y));
        af[i][2] = bfbits(f2bf(lo.z)); af[i][3] = bfbits(f2bf(lo.w));
        af[i][4] = bfbits(f2bf(hi.x)); af[i][5] = bfbits(f2bf(hi.y));
        af[i][6] = bfbits(f2bf(hi.z)); af[i][7] = bfbits(f2bf(hi.w));
      } else {
        af[i] = *(const bf16x8*)((const u16*)AsRaw + r * 32 + lq * 8);
      }
    }
#pragma unroll
    for (int j = 0; j < 4; ++j)
      bfr[j] = *(const bf16x8*)&Bs[(wc * 64 + j * 16 + lrow) * 32 + lq * 8];
#pragma unroll
    for (int i = 0; i < 4; ++i)
#pragma unroll
      for (int j = 0; j < 4; ++j)
        acc[i][j] = __builtin_amdgcn_mfma_f32_16x16x32_bf16(af[i], bfr[j], acc[i][j], 0, 0, 0);
    __syncthreads();
  }

  float* Yf = (float*)Yv;
  u16* Yh = (u16*)Yv;
#pragma unroll
  for (int i = 0; i < 4; ++i) {
#pragma unroll
    for (int j = 0; j < 4; ++j) {
      const int col = c0 + wc * 64 + j * 16 + lrow;
      const float bv = bias[col];
      float o[4];
#pragma unroll
      for (int p = 0; p < 4; ++p) o[p] = apply_act(ACT, acc[i][j][p] + bv, scale);

      if (OMODE == OM_ROW) {
#pragma unroll
        for (int p = 0; p < 4; ++p) {
          const long row = r0 + wr * 64 + i * 16 + lq * 4 + p;
          const long yi = row * NC + col;
          if (OBF16) Yh[yi] = f2bf(o[p]);
          else       Yf[yi] = o[p];
        }
      } else {  // OM_VT: vT[b][h][e][m], lane's 4 values are consecutive m
        const int b = (int)(r0 >> 12);
        const int m = (int)(r0 & 4095) + wr * 64 + i * 16 + lq * 4;
        const int h = col >> 6, e = col & 63;
        ushort4 w;
        w.x = f2bf(o[0]); w.y = f2bf(o[1]); w.z = f2bf(o[2]); w.w = f2bf(o[3]);
        *(ushort4*)(Yh + (((long)b * 8 + h) * 64 + e) * 4096 + m) = w;
      }
    }
  }
}

// ---------------------------------------------------------------------------
// weight transpose+convert: W [K,N] fp32 -> Wt [N,K] bf16
// ---------------------------------------------------------------------------
struct TArgs {
  const float* src[6];
  u16* dst[6];
  int K[6];
  int N[6];
};
__global__ __launch_bounds__(256)
void transpose_w(TArgs a)
{
  const int m = blockIdx.z;
  const int K = a.K[m], N = a.N[m];
  const int kt = blockIdx.y * 64, nt = blockIdx.x * 64;
  if (kt >= K || nt >= N) return;
  const float* src = a.src[m];
  u16* dst = a.dst[m];
  __shared__ u16 t[64][72];
  const int tx = threadIdx.x & 15, ty = threadIdx.x >> 4;
#pragma unroll
  for (int rr = 0; rr < 64; rr += 16) {
    const int k = kt + ty + rr;
    float4 v = *(const float4*)(src + (long)k * N + nt + tx * 4);
    t[tx * 4 + 0][ty + rr] = f2bf(v.x);
    t[tx * 4 + 1][ty + rr] = f2bf(v.y);
    t[tx * 4 + 2][ty + rr] = f2bf(v.z);
    t[tx * 4 + 3][ty + rr] = f2bf(v.w);
  }
  __syncthreads();
#pragma unroll
  for (int it = 0; it < 2; ++it) {
    const int s = threadIdx.x + it * 256;
    const int r = s >> 3, c = (s & 7) * 8;
    ushort4 u0 = *(ushort4*)&t[r][c];
    ushort4 u1 = *(ushort4*)&t[r][c + 4];
    *(ushort4*)(dst + (long)(nt + r) * K + kt + c) = u0;
    *(ushort4*)(dst + (long)(nt + r) * K + kt + c + 4) = u1;
  }
}

// ---------------------------------------------------------------------------
// fused MLP: per (b,h, 128 m): kaT[bh][d][m] = (elu(gelu(k@W1+b1)@W2+b2)+1)/M
// pass1: D1[c][m] = W1T . kact   (C-frag 4 vals = contiguous c -> ushort4 bounce)
// pass2: D2[d][m] = W2T . hid    (writes kaT directly)
// LDS (u16): As[128][72] @0 | W1p[128][72] @9216 | W2p[64][136] @18432
//            hid[128][136] overlays [0,17408) after pass1.
// ---------------------------------------------------------------------------
__global__ __launch_bounds__(256)
void mlp_fused(const u16* __restrict__ kact, const u16* __restrict__ W1T,
               const u16* __restrict__ W2T, const float* __restrict__ b1,
               const float* __restrict__ b2, u16* __restrict__ kaT, float invM)
{
  __shared__ __align__(16) u16 SB[27136];
  u16* As  = SB;            // [128 m][72], data in [.][0,64)
  u16* W1p = SB + 9216;     // [128 c][72], data in [.][0,64)
  u16* W2p = SB + 18432;    // [64 d][136], data in [.][0,128)
  u16* hid = SB;            // [128 m][136] overlay

  const int tid = threadIdx.x, wv = tid >> 6, lane = tid & 63;
  const int lrow = lane & 15, lq = lane >> 4;
  const int bh = blockIdx.y, b = bh >> 3, h = bh & 7;
  const int m0 = blockIdx.x * 128;
  const long kbase = ((long)b * 4096 + m0) * 512 + h * 64;

  // ---- stage (padded, plain loads) ----
#pragma unroll
  for (int i = 0; i < 4; ++i) {          // As: 1024 chunks of 8 u16
    const int c = i * 256 + tid;
    const int row = c >> 3, p = c & 7;
    uint4 v = *(const uint4*)(kact + kbase + (long)row * 512 + p * 8);
    *(uint4*)&As[row * 72 + p * 8] = v;
  }
#pragma unroll
  for (int i = 0; i < 4; ++i) {          // W1p: 1024 chunks (128 rows x 8 chunks)
    const int c = i * 256 + tid;
    const int row = c >> 3, p = c & 7;
    uint4 v = *(const uint4*)(W1T + c * 8);
    *(uint4*)&W1p[row * 72 + p * 8] = v;
  }
#pragma unroll
  for (int i = 0; i < 4; ++i) {          // W2p: 1024 chunks (64 rows x 16 chunks)  [R4 BUG FIX: was 512]
    const int c = i * 256 + tid;
    const int row = c >> 4, p = c & 15;
    uint4 v = *(const uint4*)(W2T + c * 8);
    *(uint4*)&W2p[row * 136 + p * 8] = v;
  }
  __syncthreads();

  // ---- pass 1: [128 c] x [128 m], K=64 ----
  const int c0 = (wv >> 1) * 64, mh0 = (wv & 1) * 64;
  f32x4 acc1[4][4] = {};
#pragma unroll
  for (int kt = 0; kt < 2; ++kt) {
    bf16x8 wa[4], kb[4];
#pragma unroll
    for (int i = 0; i < 4; ++i)
      wa[i] = *(const bf16x8*)&W1p[(c0 + i * 16 + lrow) * 72 + kt * 32 + lq * 8];
#pragma unroll
    for (int j = 0; j < 4; ++j)
      kb[j] = *(const bf16x8*)&As[(mh0 + j * 16 + lrow) * 72 + kt * 32 + lq * 8];
#pragma unroll
    for (int i = 0; i < 4; ++i)
#pragma unroll
      for (int j = 0; j < 4; ++j)
        acc1[i][j] = __builtin_amdgcn_mfma_f32_16x16x32_bf16(wa[i], kb[j], acc1[i][j], 0, 0, 0);
  }
  __syncthreads();   // As/W1p dead; hid overlays

  // ---- epilogue1: gelu -> hid[m][c] (4 contiguous c per lane) ----
#pragma unroll
  for (int i = 0; i < 4; ++i) {
    const int cc = c0 + i * 16 + lq * 4;
    float4 bv = *(const float4*)(b1 + cc);
#pragma unroll
    for (int j = 0; j < 4; ++j) {
      const int m = mh0 + j * 16 + lrow;
      float x0 = acc1[i][j][0] + bv.x, x1 = acc1[i][j][1] + bv.y;
      float x2 = acc1[i][j][2] + bv.z, x3 = acc1[i][j][3] + bv.w;
      ushort4 w;
      w.x = f2bf(0.5f * x0 * (1.f + erff(x0 * 0.7071067811865475f)));
      w.y = f2bf(0.5f * x1 * (1.f + erff(x1 * 0.7071067811865475f)));
      w.z = f2bf(0.5f * x2 * (1.f + erff(x2 * 0.7071067811865475f)));
      w.w = f2bf(0.5f * x3 * (1.f + erff(x3 * 0.7071067811865475f)));
      *(ushort4*)&hid[m * 136 + cc] = w;
    }
  }
  __syncthreads();

  // ---- pass 2: [64 d] x [128 m], K=128 ----
  const int d0 = (wv >> 1) * 32, mh2 = (wv & 1) * 64;
  f32x4 acc2[2][4] = {};
#pragma unroll
  for (int kt = 0; kt < 4; ++kt) {
    bf16x8 wa[2], hb[4];
#pragma unroll
    for (int i = 0; i < 2; ++i)
      wa[i] = *(const bf16x8*)&W2p[(d0 + i * 16 + lrow) * 136 + kt * 32 + lq * 8];
#pragma unroll
    for (int j = 0; j < 4; ++j)
      hb[j] = *(const bf16x8*)&hid[(mh2 + j * 16 + lrow) * 136 + kt * 32 + lq * 8];
#pragma unroll
    for (int i = 0; i < 2; ++i)
#pragma unroll
      for (int j = 0; j < 4; ++j)
        acc2[i][j] = __builtin_amdgcn_mfma_f32_16x16x32_bf16(wa[i], hb[j], acc2[i][j], 0, 0, 0);
  }

  // ---- epilogue2: elu+1, /M -> kaT[bh][d][m] ----
#pragma unroll
  for (int i = 0; i < 2; ++i) {
    const int dd = d0 + i * 16 + lq * 4;
    float4 bv = *(const float4*)(b2 + dd);
    float bva[4] = {bv.x, bv.y, bv.z, bv.w};
#pragma unroll
    for (int j = 0; j < 4; ++j) {
      const int m = m0 + mh2 + j * 16 + lrow;
#pragma unroll
      for (int p = 0; p < 4; ++p) {
        float v = acc2[i][j][p] + bva[p];
        v = ((v > 0.f) ? (v + 1.f) : __expf(v)) * invM;
        kaT[((long)bh * 64 + dd + p) * 4096 + m] = f2bf(v);
      }
    }
  }
}

// ---------------------------------------------------------------------------
// kv GEMM: D[d][e] = sum_m kaT[bh][d][m] * vT[bh][e][m]  (split-K 16)
// ksum[d] via all-ones B fragment. Partials fp32.
// ---------------------------------------------------------------------------
__global__ __launch_bounds__(256)
void kv_gemm(const u16* __restrict__ kaT, const u16* __restrict__ vT,
             float* __restrict__ kvp, float* __restrict__ ksp)
{
  const int sp = blockIdx.x;   // 0..15
  const int bh = blockIdx.y;   // 0..31
  __shared__ u16 SB[16384];
  u16* As = SB;
  u16* Bs = SB + 8192;
  const int tid = threadIdx.x, wv = tid >> 6, lane = tid & 63;
  const int lrow = lane & 15, lq = lane >> 4;
  f32x4 acc[4][4] = {};
  f32x4 accs[4] = {};
  bf16x8 ones;
#pragma unroll
  for (int z = 0; z < 8; ++z) ones[z] = (__bf16)1.0f;
  const long base = (long)bh * 64 * 4096;

  for (int ph = 0; ph < 2; ++ph) {
    const int m0 = sp * 256 + ph * 128;
#pragma unroll
    for (int i = 0; i < 4; ++i) {
      const int s = (wv * 4 + i) * 64 + lane;
      const int chunk = s >> 8, row = (s >> 2) & 63, part = s & 3;
      const long g = base + (long)row * 4096 + m0 + chunk * 32 + part * 8;
      async16(kaT + g, &As[(wv * 4 + i) * 512]);
      async16(vT + g, &Bs[(wv * 4 + i) * 512]);
    }
    __syncthreads();
    bf16x8 af[4], bfr[4];
#pragma unroll
    for (int i = 0; i < 4; ++i)
      af[i] = *(const bf16x8*)&As[wv * 2048 + (i * 16 + lrow) * 32 + lq * 8];
#pragma unroll
    for (int j = 0; j < 4; ++j)
      bfr[j] = *(const bf16x8*)&Bs[wv * 2048 + (j * 16 + lrow) * 32 + lq * 8];
#pragma unroll
    for (int i = 0; i < 4; ++i) {
#pragma unroll
      for (int j = 0; j < 4; ++j)
        acc[i][j] = __builtin_amdgcn_mfma_f32_16x16x32_bf16(af[i], bfr[j], acc[i][j], 0, 0, 0);
      accs[i] = __builtin_amdgcn_mfma_f32_16x16x32_bf16(af[i], ones, accs[i], 0, 0, 0);
    }
    __syncthreads();
  }

  float* red = (float*)SB;        // red[e][68] + ksr[64]
  float* ksr = red + 64 * 68;
  for (int w = 0; w < 4; ++w) {
    __syncthreads();
    if (wv == w) {
#pragma unroll
      for (int i = 0; i < 4; ++i) {
#pragma unroll
        for (int j = 0; j < 4; ++j) {
          const int e = j * 16 + lrow, dd = i * 16 + lq * 4;
          float* p = &red[e * 68 + dd];
          if (w == 0) { p[0] = acc[i][j][0]; p[1] = acc[i][j][1]; p[2] = acc[i][j][2]; p[3] = acc[i][j][3]; }
          else        { p[0] += acc[i][j][0]; p[1] += acc[i][j][1]; p[2] += acc[i][j][2]; p[3] += acc[i][j][3]; }
        }
        if (lrow == 0) {
          const int dd = i * 16 + lq * 4;
#pragma unroll
          for (int p2 = 0; p2 < 4; ++p2) {
            if (w == 0) ksr[dd + p2] = accs[i][p2];
            else        ksr[dd + p2] += accs[i][p2];
          }
        }
      }
    }
  }
  __syncthreads();
  float* kvo = kvp + ((long)sp * 32 + bh) * 4096;
  for (int s = tid; s < 4096; s += 256) kvo[s] = red[(s >> 6) * 68 + (s & 63)];
  if (tid < 64) ksp[(sp * 32 + bh) * 64 + tid] = ksr[tid];
}

__global__ __launch_bounds__(256)
void kv_reduce(const float* __restrict__ kvp, const float* __restrict__ ksp,
               u16* __restrict__ kvT, u16* __restrict__ ksumT)
{
  const int bh = blockIdx.x;
  const int t = threadIdx.x;
  for (int s = t; s < 4096; s += 256) {
    float v = 0.f;
#pragma unroll
    for (int sp = 0; sp < 16; ++sp) v += kvp[((long)sp * 32 + bh) * 4096 + s];
    kvT[(long)bh * 4096 + s] = f2bf(v);
  }
  if (t < 64) {
    float v = 0.f;
#pragma unroll
    for (int sp = 0; sp < 16; ++sp) v += ksp[(sp * 32 + bh) * 64 + t];
    ksumT[bh * 64 + t] = f2bf(v);
  }
}

// ---------------------------------------------------------------------------
// attn MFMA: per (bh, 256 n): out[n][e] = (q@kv) / max(q@ksum,1e-6)
// ---------------------------------------------------------------------------
__global__ __launch_bounds__(256)
void attn_mfma(const u16* __restrict__ q, const u16* __restrict__ kvT,
               const u16* __restrict__ ksumT, u16* __restrict__ attn)
{
  __shared__ u16 SB[17408];
  const int tid = threadIdx.x, wv = tid >> 6, lane = tid & 63;
  const int lrow = lane & 15, lq = lane >> 4;
  const int n0 = blockIdx.x * 256;
  const int bh = blockIdx.y, b = bh >> 3, h = bh & 7;
  u16* As = SB;

#pragma unroll
  for (int half = 0; half < 2; ++half)
#pragma unroll
    for (int i = 0; i < 4; ++i) {
      const int s = (wv * 4 + i) * 64 + lane;
      async16(q + ((long)(b * 4096 + n0 + (s >> 2))) * 512 + h * 64 + half * 32 + (s & 3) * 8,
              &As[half * 8192 + (wv * 4 + i) * 512]);
    }
  bf16x8 bfr[2][4], ks[2];
#pragma unroll
  for (int half = 0; half < 2; ++half) {
#pragma unroll
    for (int j = 0; j < 4; ++j)
      bfr[half][j] = *(const bf16x8*)(kvT + ((long)bh * 64 + j * 16 + lrow) * 64 + half * 32 + lq * 8);
    ks[half] = *(const bf16x8*)(ksumT + bh * 64 + half * 32 + lq * 8);
  }
  __syncthreads();

  f32x4 acc[4][4] = {};
  f32x4 accd[4] = {};
#pragma unroll
  for (int half = 0; half < 2; ++half) {
    bf16x8 af[4];
#pragma unroll
    for (int i = 0; i < 4; ++i)
      af[i] = *(const bf16x8*)&As[half * 8192 + (wv * 64 + i * 16 + lrow) * 32 + lq * 8];
#pragma unroll
    for (int i = 0; i < 4; ++i) {
#pragma unroll
      for (int j = 0; j < 4; ++j)
        acc[i][j] = __builtin_amdgcn_mfma_f32_16x16x32_bf16(af[i], bfr[half][j], acc[i][j], 0, 0, 0);
      accd[i] = __builtin_amdgcn_mfma_f32_16x16x32_bf16(af[i], ks[half], accd[i], 0, 0, 0);
    }
  }
  __syncthreads();

  u16* LT = SB;   // LT[wv][64 e][68 n]
#pragma unroll
  for (int i = 0; i < 4; ++i) {
    float dinv[4];
#pragma unroll
    for (int p = 0; p < 4; ++p) dinv[p] = 1.f / fmaxf(accd[i][p], 1e-6f);
#pragma unroll
    for (int j = 0; j < 4; ++j) {
      const int e = j * 16 + lrow;
      const int nl0 = i * 16 + lq * 4;
      ushort4 w;
      float x0 = acc[i][j][0] * dinv[0], x1 = acc[i][j][1] * dinv[1];
      float x2 = acc[i][j][2] * dinv[2], x3 = acc[i][j][3] * dinv[3];
      if (!(x0 == x0)) x0 = 0.f;
      if (!(x1 == x1)) x1 = 0.f;
      if (!(x2 == x2)) x2 = 0.f;
      if (!(x3 == x3)) x3 = 0.f;
      w.x = f2bf(fminf(65000.f, fmaxf(-65000.f, x0)));
      w.y = f2bf(fminf(65000.f, fmaxf(-65000.f, x1)));
      w.z = f2bf(fminf(65000.f, fmaxf(-65000.f, x2)));
      w.w = f2bf(fminf(65000.f, fmaxf(-65000.f, x3)));
      *(ushort4*)&LT[wv * 4352 + e * 68 + nl0] = w;
    }
  }
  __syncthreads();
#pragma unroll
  for (int it = 0; it < 8; ++it) {
    const int c = it * 256 + tid;
    const int n = c & 255, ec = c >> 8;
    const int wr2 = n >> 6, nl = n & 63;
    ushort4 w0, w1;
    w0.x = LT[wr2 * 4352 + (ec * 8 + 0) * 68 + nl];
    w0.y = LT[wr2 * 4352 + (ec * 8 + 1) * 68 + nl];
    w0.z = LT[wr2 * 4352 + (ec * 8 + 2) * 68 + nl];
    w0.w = LT[wr2 * 4352 + (ec * 8 + 3) * 68 + nl];
    w1.x = LT[wr2 * 4352 + (ec * 8 + 4) * 68 + nl];
    w1.y = LT[wr2 * 4352 + (ec * 8 + 5) * 68 + nl];
    w1.z = LT[wr2 * 4352 + (ec * 8 + 6) * 68 + nl];
    w1.w = LT[wr2 * 4352 + (ec * 8 + 7) * 68 + nl];
    u16* dst = attn + ((long)(b * 4096 + n0 + n)) * 512 + h * 64 + ec * 8;
    *(ushort4*)dst = w0;
    *(ushort4*)(dst + 4) = w1;
  }
}

// ---------------------------------------------------------------------------
static constexpr long U = 8388608;   // elems of one [4,4096,512] tensor

extern "C" void kernel_launch(void* const* d_in, const int* in_sizes, int n_in,
                              void* d_out, int out_size, void* d_ws, size_t ws_size,
                              hipStream_t stream)
{
  const float* query = (const float*)d_in[0];
  const float* key   = (const float*)d_in[1];
  const float* value = (const float*)d_in[2];
  const float* Wq = (const float*)d_in[3];
  const float* bq = (const float*)d_in[4];
  const float* Wk = (const float*)d_in[5];
  const float* bk = (const float*)d_in[6];
  const float* Wv = (const float*)d_in[7];
  const float* bv = (const float*)d_in[8];
  const float* W1 = (const float*)d_in[9];
  const float* b1 = (const float*)d_in[10];
  const float* W2 = (const float*)d_in[11];
  const float* b2 = (const float*)d_in[12];
  const float* Wo = (const float*)d_in[13];
  const float* bo = (const float*)d_in[14];

  u16* wsh = (u16*)d_ws;
  u16* qact = wsh;           // [16384,512] bf16
  u16* kact = wsh + U;
  u16* vT   = wsh + 2 * U;   // vT[b][h][e][m]
  u16* kaT  = wsh + 3 * U;   // [32][64][4096]
  u16* attn = wsh + 4 * U;

  float* fp  = (float*)(wsh + 5 * U);
  float* kvp = fp;                     // 16*32*4096
  float* ksp = fp + 2097152;           // 16*32*64
  u16* kvTg   = (u16*)(fp + 2129920);  // 32*4096
  u16* ksumTg = kvTg + 131072;         // 32*64
  u16* wtb = ksumTg + 2048;
  u16* WqT = wtb;                      // [512,512]
  u16* WkT = wtb + 262144;
  u16* WvT = wtb + 524288;
  u16* WoT = wtb + 786432;
  u16* W1T = wtb + 1048576;            // [128,64]
  u16* W2T = wtb + 1056768;            // [64,128]

  dim3 blk(256);
  const float invM = 1.f / 4096.f;

  TArgs ta;
  ta.src[0] = Wq; ta.dst[0] = WqT; ta.K[0] = 512; ta.N[0] = 512;
  ta.src[1] = Wk; ta.dst[1] = WkT; ta.K[1] = 512; ta.N[1] = 512;
  ta.src[2] = Wv; ta.dst[2] = WvT; ta.K[2] = 512; ta.N[2] = 512;
  ta.src[3] = Wo; ta.dst[3] = WoT; ta.K[3] = 512; ta.N[3] = 512;
  ta.src[4] = W1; ta.dst[4] = W1T; ta.K[4] = 64;  ta.N[4] = 128;
  ta.src[5] = W2; ta.dst[5] = W2T; ta.K[5] = 128; ta.N[5] = 64;
  transpose_w<<<dim3(8, 8, 6), blk, 0, stream>>>(ta);

  // projections straight from fp32 inputs (in-GEMM RNE cvt)
  gemm_bf16<128,128,512,2,2,ACT_ELU1,1,OM_ROW,1><<<dim3(4,128), blk, 0, stream>>>(query, WqT, bq, qact, 512, 1.f);
  gemm_bf16<128,128,512,2,2,ACT_ELU1,1,OM_ROW,1><<<dim3(4,128), blk, 0, stream>>>(key,   WkT, bk, kact, 512, 1.f);
  gemm_bf16<128,128,512,2,2,ACT_ID,  1,OM_VT, 1><<<dim3(4,128), blk, 0, stream>>>(value, WvT, bv, vT,   512, 1.f);
  // fused rank-expansion MLP -> kaT
  mlp_fused<<<dim3(32,32), blk, 0, stream>>>(kact, W1T, W2T, b1, b2, kaT, invM);
  // kv context + ksum (MFMA split-K 16) then reduce to bf16
  kv_gemm<<<dim3(16,32), blk, 0, stream>>>(kaT, vT, kvp, ksp);
  kv_reduce<<<dim3(32), blk, 0, stream>>>(kvp, ksp, kvTg, ksumTg);
  // attention output
  attn_mfma<<<dim3(16,32), blk, 0, stream>>>(qact, kvTg, ksumTg, attn);
  // final projection -> d_out fp32
  gemm_bf16<128,128,512,2,2,ACT_ID,0,OM_ROW,0><<<dim3(4,128), blk, 0, stream>>>(attn, WoT, bo, (float*)d_out, 512, 1.f);
}